// Round 5
// baseline (63.983 us; speedup 1.0000x reference)
//
#include <hip/hip_runtime.h>

// loss = sum_ij C[i,j]*(t[i]+t[j]-2*G[i,j]) / (B*(n_pos+1e-8))
//   t[k] = sum_b P[b,k]^2 (fp32, fused into staging via shuffle reduce)
//   G    = P^T P via bf16 MFMA 16x16x32 (layouts HW-verified R3/R4)
// tile_kernel: 1024 blocks (32x32 C-tiles) x 256 thr, 4 blocks/CU.
//   R5 change vs R4: the serial wave-0 t-pass (128 strided LDS reads @8-way
//   conflict, ~1us, 3 waves idle) is replaced by in-register per-column
//   square partials during staging + __shfl_xor reduce + tiny LDS combine
//   that overlaps the MFMA phase.
// reduce_kernel: 1024 partials -> out.

#define B_DIM 128
#define N_DIM 1024
#define PAD 136   // u16 row stride: 272 B = 17*16 -> b64/b128 aligned

typedef __bf16 bf16x8 __attribute__((ext_vector_type(8)));
typedef float  f32x4  __attribute__((ext_vector_type(4)));

static __device__ inline unsigned short f2bf(float f) {
    union { float f; unsigned u; } v; v.f = f;
    return (unsigned short)((v.u + 0x7fffu + ((v.u >> 16) & 1u)) >> 16);  // RNE
}

__global__ __launch_bounds__(256) void tile_kernel(const float* __restrict__ P,
                                                   const float* __restrict__ C,
                                                   float* __restrict__ psum,
                                                   unsigned* __restrict__ pcnt) {
    __shared__ unsigned short PT[64][PAD];     // rows 0-31 i-panel, 32-63 j-panel
    __shared__ float tpart[2][4][8][4];        // pan, wave, q, comp (1 KB)
    __shared__ float ts[64];                   // t for [i-cols | j-cols]
    __shared__ float wsum[4];
    __shared__ unsigned wcnt[4];

    const int tid = threadIdx.x, bid = blockIdx.x;
    const int l = tid & 63, w = tid >> 6;
    const int i0 = (bid >> 5) * 32, j0 = (bid & 31) * 32;
    const int wr = w >> 1, wc = w & 1;         // wave's 16x16 quadrant

    // ---- issue C loads first (consumed in epilogue; latency hidden) ----
    const int gcol = j0 + wc * 16 + (l & 15);
    const int grow = i0 + wr * 16 + (l >> 4) * 4;
    float cv0 = C[(grow + 0) * N_DIM + gcol];
    float cv1 = C[(grow + 1) * N_DIM + gcol];
    float cv2 = C[(grow + 2) * N_DIM + gcol];
    float cv3 = C[(grow + 3) * N_DIM + gcol];

    // ---- stage panels (fp32 coalesced -> bf16 transposed LDS) + t partials --
    const float4* P4 = (const float4*)P;
    const int q   = tid & 7;       // col-quad within 32-col panel
    const int bhi = tid >> 3;      // 0..31: b = (r&3)*32 + bhi
    float4 sq0 = {0.f, 0.f, 0.f, 0.f};   // i-panel per-col squares (fp32)
    float4 sq1 = {0.f, 0.f, 0.f, 0.f};   // j-panel
#pragma unroll
    for (int r = 0; r < 8; ++r) {
        const int pan = (r < 4) ? 0 : 1;
        const int p0  = (r < 4) ? i0 : j0;
        const int b   = (r & 3) * 32 + bhi;
        float4 v = P4[b * (N_DIM / 4) + (p0 >> 2) + q];
        PT[pan * 32 + q * 4 + 0][b] = f2bf(v.x);
        PT[pan * 32 + q * 4 + 1][b] = f2bf(v.y);
        PT[pan * 32 + q * 4 + 2][b] = f2bf(v.z);
        PT[pan * 32 + q * 4 + 3][b] = f2bf(v.w);
        if (pan == 0) {
            sq0.x = fmaf(v.x, v.x, sq0.x); sq0.y = fmaf(v.y, v.y, sq0.y);
            sq0.z = fmaf(v.z, v.z, sq0.z); sq0.w = fmaf(v.w, v.w, sq0.w);
        } else {
            sq1.x = fmaf(v.x, v.x, sq1.x); sq1.y = fmaf(v.y, v.y, sq1.y);
            sq1.z = fmaf(v.z, v.z, sq1.z); sq1.w = fmaf(v.w, v.w, sq1.w);
        }
    }
    // reduce per-col squares over the 8 b-lane-groups (lanes q, q+8, ..., q+56)
#pragma unroll
    for (int off = 8; off <= 32; off <<= 1) {
        sq0.x += __shfl_xor(sq0.x, off); sq0.y += __shfl_xor(sq0.y, off);
        sq0.z += __shfl_xor(sq0.z, off); sq0.w += __shfl_xor(sq0.w, off);
        sq1.x += __shfl_xor(sq1.x, off); sq1.y += __shfl_xor(sq1.y, off);
        sq1.z += __shfl_xor(sq1.z, off); sq1.w += __shfl_xor(sq1.w, off);
    }
    if ((l >> 3) == 0) {                       // lanes 0..7: l == q
        *(float4*)&tpart[0][w][l][0] = sq0;
        *(float4*)&tpart[1][w][l][0] = sq1;
    }
    __syncthreads();                           // PT + tpart complete

    // ---- ts combine (threads 0..63) overlaps fragment loads of all waves ---
    if (tid < 64) {
        const int pan = tid >> 5, cq = tid & 31;
        ts[tid] = tpart[pan][0][cq >> 2][cq & 3] + tpart[pan][1][cq >> 2][cq & 3]
                + tpart[pan][2][cq >> 2][cq & 3] + tpart[pan][3][cq >> 2][cq & 3];
    }

    // ---- fragments + MFMA (layouts HW-verified R3/R4) ----
    f32x4 acc = {0.f, 0.f, 0.f, 0.f};
    const int ar = wr * 16 + (l & 15);         // i-panel LDS row
    const int br = 32 + wc * 16 + (l & 15);    // j-panel LDS row
    const int ko = (l >> 4) * 8;
#pragma unroll
    for (int s = 0; s < 4; ++s) {
        bf16x8 af = *(const bf16x8*)&PT[ar][s * 32 + ko];
        bf16x8 bf = *(const bf16x8*)&PT[br][s * 32 + ko];
        acc = __builtin_amdgcn_mfma_f32_16x16x32_bf16(af, bf, acc, 0, 0, 0);
    }
    __syncthreads();                           // ts visible to all

    // ---- epilogue: C*(ti+tj-2G) + count ----
    const float tj = ts[32 + wc * 16 + (l & 15)];
    const int rb = wr * 16 + (l >> 4) * 4;
    float loss = 0.f;
    loss = fmaf(cv0, ts[rb + 0] + tj - 2.f * acc[0], loss);
    loss = fmaf(cv1, ts[rb + 1] + tj - 2.f * acc[1], loss);
    loss = fmaf(cv2, ts[rb + 2] + tj - 2.f * acc[2], loss);
    loss = fmaf(cv3, ts[rb + 3] + tj - 2.f * acc[3], loss);
    unsigned cnt = (cv0 > 0.f) + (cv1 > 0.f) + (cv2 > 0.f) + (cv3 > 0.f);

#pragma unroll
    for (int off = 32; off > 0; off >>= 1) {
        loss += __shfl_down(loss, off);
        cnt  += __shfl_down(cnt, off);
    }
    if (l == 0) { wsum[w] = loss; wcnt[w] = cnt; }
    __syncthreads();
    if (tid == 0) {
        psum[bid] = wsum[0] + wsum[1] + wsum[2] + wsum[3];
        pcnt[bid] = wcnt[0] + wcnt[1] + wcnt[2] + wcnt[3];
    }
}

__global__ __launch_bounds__(256) void reduce_kernel(const float* __restrict__ psum,
                                                     const unsigned* __restrict__ pcnt,
                                                     float* __restrict__ out) {
    __shared__ double ws_[4];
    __shared__ unsigned wc_[4];
    const int tid = threadIdx.x;
    double s = 0.0; unsigned c = 0;
#pragma unroll
    for (int r = 0; r < 4; ++r) {
        s += (double)psum[r * 256 + tid];
        c += pcnt[r * 256 + tid];
    }
#pragma unroll
    for (int off = 32; off > 0; off >>= 1) {
        s += __shfl_down(s, off);
        c += __shfl_down(c, off);
    }
    const int wave = tid >> 6, lane = tid & 63;
    if (lane == 0) { ws_[wave] = s; wc_[wave] = c; }
    __syncthreads();
    if (tid == 0) {
        double st = ws_[0] + ws_[1] + ws_[2] + ws_[3];
        double ct = (double)(wc_[0] + wc_[1] + wc_[2] + wc_[3]);
        out[0] = (float)(st / ((double)B_DIM * (ct + 1e-8)));
    }
}

extern "C" void kernel_launch(void* const* d_in, const int* in_sizes, int n_in,
                              void* d_out, int out_size, void* d_ws, size_t ws_size,
                              hipStream_t stream) {
    const float* probs = (const float*)d_in[0];   // [128, 1024] fp32
    const float* co    = (const float*)d_in[1];   // [1024, 1024] fp32
    float* out = (float*)d_out;

    float*    psum = (float*)d_ws;                        // 1024 * 4 B
    unsigned* pcnt = (unsigned*)((char*)d_ws + 4096);     // 1024 * 4 B

    tile_kernel<<<1024, 256, 0, stream>>>(probs, co, psum, pcnt);
    reduce_kernel<<<1, 256, 0, stream>>>(psum, pcnt, out);
}

// Round 6
// 61.762 us; speedup vs baseline: 1.0360x; 1.0360x over previous
//
#include <hip/hip_runtime.h>

// loss = sum_ij C[i,j]*(t[i]+t[j]-2*G[i,j]) / (B*(n_pos+1e-8))
//   t[k] = sum_b p̂[b,k]^2 (bf16-consistent, wave-0 pass — R4's measured-best)
//   G    = P^T P via bf16 MFMA 16x16x32 (layouts HW-verified R3/R4)
// R6: W is symmetric in (i,j) -> only upper-triangle 32x32 tiles computed.
//   528 blocks (ti<=tj). Off-diag tiles apply (C_ij + C_ji): the transposed
//   C read per thread is one contiguous float4 (C[gcol][grow..grow+3]) due
//   to the MFMA C/D fragment layout. Halves staging+MFMA work vs R4/R5.
// reduce_kernel: 528 partials -> out.

#define B_DIM 128
#define N_DIM 1024
#define PAD 136   // u16 row stride: 272 B = 17*16 -> b64/b128 aligned
#define NBLK 528  // 32*33/2

typedef __bf16 bf16x8 __attribute__((ext_vector_type(8)));
typedef float  f32x4  __attribute__((ext_vector_type(4)));

static __device__ inline unsigned short f2bf(float f) {
    union { float f; unsigned u; } v; v.f = f;
    return (unsigned short)((v.u + 0x7fffu + ((v.u >> 16) & 1u)) >> 16);  // RNE
}
static __device__ inline float bf2f(unsigned short h) {
    union { unsigned u; float f; } v; v.u = ((unsigned)h) << 16;
    return v.f;
}

__global__ __launch_bounds__(256) void tile_kernel(const float* __restrict__ P,
                                                   const float* __restrict__ C,
                                                   float* __restrict__ psum,
                                                   unsigned* __restrict__ pcnt) {
    __shared__ unsigned short PT[64][PAD];   // rows 0-31: i-panel, 32-63: j-panel
    __shared__ float ts[64];
    __shared__ float wsum[4];
    __shared__ unsigned wcnt[4];

    const int tid = threadIdx.x, bid = blockIdx.x;
    const int l = tid & 63, w = tid >> 6;

    // ---- upper-triangle tile index: bid -> (ti, tj), ti <= tj ----
    int ti = 0, rem = bid, rowlen = 32;
    while (rem >= rowlen) { rem -= rowlen; --rowlen; ++ti; }
    const int tj = ti + rem;
    const int i0 = ti * 32, j0 = tj * 32;
    const bool offdiag = (ti != tj);

    const int wr = w >> 1, wc = w & 1;       // wave's 16x16 quadrant

    // ---- issue C loads first (consumed in epilogue; latency hidden) ----
    const int gcol = j0 + wc * 16 + (l & 15);
    const int grow = i0 + wr * 16 + (l >> 4) * 4;
    float cv0 = C[(grow + 0) * N_DIM + gcol];
    float cv1 = C[(grow + 1) * N_DIM + gcol];
    float cv2 = C[(grow + 2) * N_DIM + gcol];
    float cv3 = C[(grow + 3) * N_DIM + gcol];
    f32x4 cvT = {0.f, 0.f, 0.f, 0.f};
    if (offdiag) cvT = *(const f32x4*)&C[(size_t)gcol * N_DIM + grow];  // C[j,i] row-contig

    // ---- stage both panels: fp32 coalesced reads -> bf16 transposed LDS ----
    const float4* P4 = (const float4*)P;
#pragma unroll
    for (int r = 0; r < 8; ++r) {
        const int pan = (r < 4) ? 0 : 1;
        const int p0  = (r < 4) ? i0 : j0;
        const int b   = (r & 3) * 32 + (tid >> 3);   // batch row
        const int q   = tid & 7;                     // col-quad within panel
        float4 v = P4[b * (N_DIM / 4) + (p0 >> 2) + q];
        PT[pan * 32 + q * 4 + 0][b] = f2bf(v.x);
        PT[pan * 32 + q * 4 + 1][b] = f2bf(v.y);
        PT[pan * 32 + q * 4 + 2][b] = f2bf(v.z);
        PT[pan * 32 + q * 4 + 3][b] = f2bf(v.w);
    }
    __syncthreads();

    // ---- wave 0: t per staged column (bf16-consistent, fp32 accum) ----
    if (tid < 64) {
        float s = 0.f;
#pragma unroll 8
        for (int b = 0; b < B_DIM; ++b) {
            float v = bf2f(PT[tid][b]);
            s = fmaf(v, v, s);
        }
        ts[tid] = s;
    }

    // ---- fragments + MFMA (layouts HW-verified R3/R4) ----
    f32x4 acc = {0.f, 0.f, 0.f, 0.f};
    const int ar = wr * 16 + (l & 15);         // i-panel LDS row
    const int br = 32 + wc * 16 + (l & 15);    // j-panel LDS row
    const int ko = (l >> 4) * 8;
#pragma unroll
    for (int s = 0; s < 4; ++s) {
        bf16x8 af = *(const bf16x8*)&PT[ar][s * 32 + ko];
        bf16x8 bf = *(const bf16x8*)&PT[br][s * 32 + ko];
        acc = __builtin_amdgcn_mfma_f32_16x16x32_bf16(af, bf, acc, 0, 0, 0);
    }
    __syncthreads();   // ts visible to all

    // ---- epilogue: (C_ij [+ C_ji]) * (ti+tj-2G) + count ----
    const float tjc = ts[32 + wc * 16 + (l & 15)];
    const int rb = wr * 16 + (l >> 4) * 4;
    float w0 = ts[rb + 0] + tjc - 2.f * acc[0];
    float w1 = ts[rb + 1] + tjc - 2.f * acc[1];
    float w2 = ts[rb + 2] + tjc - 2.f * acc[2];
    float w3 = ts[rb + 3] + tjc - 2.f * acc[3];
    float loss = 0.f;
    unsigned cnt = (cv0 > 0.f) + (cv1 > 0.f) + (cv2 > 0.f) + (cv3 > 0.f);
    if (offdiag) {
        loss = fmaf(cv0 + cvT[0], w0, loss);
        loss = fmaf(cv1 + cvT[1], w1, loss);
        loss = fmaf(cv2 + cvT[2], w2, loss);
        loss = fmaf(cv3 + cvT[3], w3, loss);
        cnt += (cvT[0] > 0.f) + (cvT[1] > 0.f) + (cvT[2] > 0.f) + (cvT[3] > 0.f);
    } else {
        loss = fmaf(cv0, w0, loss);
        loss = fmaf(cv1, w1, loss);
        loss = fmaf(cv2, w2, loss);
        loss = fmaf(cv3, w3, loss);
    }

#pragma unroll
    for (int off = 32; off > 0; off >>= 1) {
        loss += __shfl_down(loss, off);
        cnt  += __shfl_down(cnt, off);
    }
    if (l == 0) { wsum[w] = loss; wcnt[w] = cnt; }
    __syncthreads();
    if (tid == 0) {
        psum[bid] = wsum[0] + wsum[1] + wsum[2] + wsum[3];
        pcnt[bid] = wcnt[0] + wcnt[1] + wcnt[2] + wcnt[3];
    }
}

__global__ __launch_bounds__(256) void reduce_kernel(const float* __restrict__ psum,
                                                     const unsigned* __restrict__ pcnt,
                                                     float* __restrict__ out) {
    __shared__ double ws_[4];
    __shared__ unsigned wc_[4];
    const int tid = threadIdx.x;
    double s = (double)psum[tid] + (double)psum[tid + 256];
    unsigned c = pcnt[tid] + pcnt[tid + 256];
    if (tid < NBLK - 512) { s += (double)psum[tid + 512]; c += pcnt[tid + 512]; }
#pragma unroll
    for (int off = 32; off > 0; off >>= 1) {
        s += __shfl_down(s, off);
        c += __shfl_down(c, off);
    }
    const int wave = tid >> 6, lane = tid & 63;
    if (lane == 0) { ws_[wave] = s; wc_[wave] = c; }
    __syncthreads();
    if (tid == 0) {
        double st = ws_[0] + ws_[1] + ws_[2] + ws_[3];
        double ct = (double)(wc_[0] + wc_[1] + wc_[2] + wc_[3]);
        out[0] = (float)(st / ((double)B_DIM * (ct + 1e-8)));
    }
}

extern "C" void kernel_launch(void* const* d_in, const int* in_sizes, int n_in,
                              void* d_out, int out_size, void* d_ws, size_t ws_size,
                              hipStream_t stream) {
    const float* probs = (const float*)d_in[0];   // [128, 1024] fp32
    const float* co    = (const float*)d_in[1];   // [1024, 1024] fp32
    float* out = (float*)d_out;

    float*    psum = (float*)d_ws;                        // 528 * 4 B
    unsigned* pcnt = (unsigned*)((char*)d_ws + 2112 + 64);// 528 * 4 B (offset 2176, 64B-aligned)

    tile_kernel<<<NBLK, 256, 0, stream>>>(probs, co, psum, pcnt);
    reduce_kernel<<<1, 256, 0, stream>>>(psum, pcnt, out);
}